// Round 3
// baseline (181.518 us; speedup 1.0000x reference)
//
#include <hip/hip_runtime.h>
#include <hip/hip_bf16.h>
#include <stdint.h>

typedef __attribute__((ext_vector_type(8))) short short8;
typedef __attribute__((ext_vector_type(8))) unsigned short ushort8;
typedef __attribute__((ext_vector_type(4))) float f32x4;
typedef __attribute__((ext_vector_type(4))) int int4v;

#define NHEAD 32
#define SEQ   2048
#define HN    128

static constexpr float INV_NORM = 0.08838834764831845f;  // 1/sqrt(128), folded into Q

__device__ __forceinline__ unsigned short f2bf(float f) {
  union { float f; unsigned u; } v; v.f = f;
  unsigned r = v.u + 0x7fffu + ((v.u >> 16) & 1u);   // RNE
  return (unsigned short)(r >> 16);
}

__device__ __forceinline__ f32x4 mfma16(short8 a, short8 b, f32x4 c) {
  return __builtin_amdgcn_mfma_f32_16x16x32_bf16(a, b, c, 0, 0, 0);
}

__device__ __forceinline__ void gl_lds16(const void* g, void* l) {
  __builtin_amdgcn_global_load_lds(
      (const __attribute__((address_space(1))) unsigned int*)g,
      (__attribute__((address_space(3))) unsigned int*)l, 16, 0, 0);
}

// ---- fused prep (unchanged, R3/R5-proven):
__global__ __launch_bounds__(256) void prep_kv(const float* __restrict__ K,
                                               const float* __restrict__ V,
                                               unsigned short* __restrict__ kswz,
                                               unsigned short* __restrict__ vT) {
  __shared__ unsigned short lds[128 * 136];
  int bid = blockIdx.x;
  int tid = threadIdx.x;
  if (bid < 4096) {
    int idx = bid * 256 + tid;     // chunk id: 32*2048*16
    int cl = idx & 15;
    int t  = (idx >> 4) & 2047;
    int bn = idx >> 15;
    const float4* src = (const float4*)(K + ((size_t)t * 32 + bn) * 128 + cl * 8);
    float4 a = src[0], b = src[1];
    ushort8 o;
    o[0]=f2bf(a.x); o[1]=f2bf(a.y); o[2]=f2bf(a.z); o[3]=f2bf(a.w);
    o[4]=f2bf(b.x); o[5]=f2bf(b.y); o[6]=f2bf(b.z); o[7]=f2bf(b.w);
    *(ushort8*)(kswz + ((size_t)bn * 2048 + t) * 128 + ((cl ^ (t & 7)) * 8)) = o;
  } else {
    int vb = bid - 4096;
    int bn = vb >> 4;
    int t0 = (vb & 15) << 7;
    int r = tid >> 1, h0 = (tid & 1) * 64;
    const float* src = V + ((size_t)(t0 + r) * 32 + bn) * 128 + h0;
#pragma unroll
    for (int j = 0; j < 8; ++j) {
      float4 a = *(const float4*)(src + j * 8);
      float4 b = *(const float4*)(src + j * 8 + 4);
      ushort8 o;
      o[0]=f2bf(a.x); o[1]=f2bf(a.y); o[2]=f2bf(a.z); o[3]=f2bf(a.w);
      o[4]=f2bf(b.x); o[5]=f2bf(b.y); o[6]=f2bf(b.z); o[7]=f2bf(b.w);
      *(ushort8*)&lds[r * 136 + h0 + j * 8] = o;
    }
    __syncthreads();
    int h = tid >> 1, ts = (tid & 1) * 64;
    unsigned short tmp[64];
#pragma unroll
    for (int j = 0; j < 64; ++j) {
      int p = j & 31;
      int tloc = ((p >> 3) & 3) * 4 + ((p >> 2) & 1) * 16 + (p & 3);
      tmp[j] = lds[(ts + (j & 32) + tloc) * 136 + h];
    }
    ushort8* dst = (ushort8*)(vT + ((size_t)bn * 128 + h) * 2048 + t0 + ts);
#pragma unroll
    for (int j = 0; j < 8; ++j) dst[j] = *(ushort8*)&tmp[j * 8];
  }
}

// ---- fragment/softmax helpers --------------------------------------------
__device__ __forceinline__ void read_kf(const char* kb, int l15, int hi,
                                        short8 (&kf)[2][4]) {
  int xr = (l15 & 7) << 4;      // (row&7)==(l15&7): nt offset is mult of 16
#pragma unroll
  for (int nt = 0; nt < 2; ++nt) {
    const char* krow = kb + (nt * 16 + l15) * 256;
#pragma unroll
    for (int kk = 0; kk < 4; ++kk)
      kf[nt][kk] = *(const short8*)(krow + (((kk * 4 + hi) * 16) ^ xr));
  }
}

__device__ __forceinline__ void read_vf(const char* vbh, int l15, int hi,
                                        short8 (&vf)[8]) {
#pragma unroll
  for (int ht = 0; ht < 8; ++ht)
    vf[ht] = *(const short8*)(vbh + (ht * 16 + l15) * 64 +
                              ((((l15 >> 1) + hi) & 3) * 16));
}

__device__ __forceinline__ short8 packp(const float (&e)[8], float& da) {
  da += ((e[0] + e[1]) + (e[2] + e[3])) + ((e[4] + e[5]) + (e[6] + e[7]));
  unsigned w0, w1, w2, w3;
  asm("v_cvt_pk_bf16_f32 %0, %1, %2" : "=v"(w0) : "v"(e[0]), "v"(e[1]));
  asm("v_cvt_pk_bf16_f32 %0, %1, %2" : "=v"(w1) : "v"(e[2]), "v"(e[3]));
  asm("v_cvt_pk_bf16_f32 %0, %1, %2" : "=v"(w2) : "v"(e[4]), "v"(e[5]));
  asm("v_cvt_pk_bf16_f32 %0, %1, %2" : "=v"(w3) : "v"(e[6]), "v"(e[7]));
  union { int4v u; short8 s; } pk;
  pk.u = (int4v){(int)w0, (int)w1, (int)w2, (int)w3};
  return pk.s;
}

// Q pre-scaled by 1/sqrt(128): probability = exp(S) directly.
__device__ __forceinline__ short8 softp_m(const f32x4 (&sv)[2], int t0h, int qbase,
                                          int l15, int hi, float& da) {
  float e[8];
#pragma unroll
  for (int nt = 0; nt < 2; ++nt)
#pragma unroll
    for (int i = 0; i < 4; ++i) {
      float x = __expf(sv[nt][i]);
      int kv = t0h + nt * 16 + hi * 4 + i;
      e[nt * 4 + i] = (kv <= qbase + l15) ? x : 0.0f;
    }
  return packp(e, da);
}

__device__ __forceinline__ short8 softp_u(const f32x4 (&sv)[2], float& da) {
  float e[8];
#pragma unroll
  for (int nt = 0; nt < 2; ++nt)
#pragma unroll
    for (int i = 0; i < 4; ++i)
      e[nt * 4 + i] = __expf(sv[nt][i]);
  return packp(e, da);
}

// ---- main: 1024 blocks x 256 threads, each block = ONE 64-row q-tile,
// 4 waves x 16 q-rows, KVB=32 double-buffered (32KB LDS) -> 4 blocks/CU,
// 16 waves/CU (4/SIMD) vs 8/CU before.  Per-wave state halved vs the
// pair design (acc[8]+qf[4] = 48 regs) so the 128-VGPR cap holds w/o spill.
// Work balance: any co-resident set {z, z+8, z+16, z+24} sums to 62 units
// (stride-256 co-residency model, proven by R0's pair layout); heaviest
// blocks get lowest bids (dispatched first).
__global__ __launch_bounds__(256, 4) void attn_main(const float* __restrict__ Q,
                                                    const unsigned short* __restrict__ kswz,
                                                    const unsigned short* __restrict__ vT,
                                                    float* __restrict__ out) {
  // LDS: K 2x8KB | V 2x8KB = 32768
  __shared__ char smem[32768];
  int tid = threadIdx.x;
  int lane = tid & 63;
  int w = tid >> 6;
  int l15 = lane & 15;
  int hi = lane >> 4;

  int bid = blockIdx.x;
  int bn = bid & 31;                    // head -> XCD bid%8 = bn%8 (stable)
  int z = bid >> 5;                     // [0,32)
  int g = z & 7, s = z >> 3;
  int qt = (s == 0) ? (31 - g) : (s == 1) ? (16 + g) : (s == 2) ? (15 - g) : g;
  int qb = qt * 64 + w * 16;            // this wave's 16 q-rows
  int ntile = 2 * qt + 2;               // 32-kv tiles

  // Q B-fragments, PRE-SCALED by 1/sqrt(128): softmax is exp(S) direct.
  short8 qf[4];
  {
    const float* qrow = Q + ((size_t)(qb + l15) * 32 + bn) * 128;
#pragma unroll
    for (int kk = 0; kk < 4; ++kk) {
      float4 a = *(const float4*)(qrow + kk * 32 + hi * 8);
      float4 b = *(const float4*)(qrow + kk * 32 + hi * 8 + 4);
      short8 o;
      o[0]=(short)f2bf(a.x*INV_NORM); o[1]=(short)f2bf(a.y*INV_NORM);
      o[2]=(short)f2bf(a.z*INV_NORM); o[3]=(short)f2bf(a.w*INV_NORM);
      o[4]=(short)f2bf(b.x*INV_NORM); o[5]=(short)f2bf(b.y*INV_NORM);
      o[6]=(short)f2bf(b.z*INV_NORM); o[7]=(short)f2bf(b.w*INV_NORM);
      qf[kk] = o;
    }
  }

  f32x4 zz = {0.f, 0.f, 0.f, 0.f};
  f32x4 acc[8];
#pragma unroll
  for (int ht = 0; ht < 8; ++ht) acc[ht] = zz;
  float dacc = 0.f;

  const char* kg = (const char*)(kswz + (size_t)bn * 2048 * 128);
  const char* vg = (const char*)(vT + (size_t)bn * 128 * 2048);

  auto stage = [&](int buf, int t) {  // stage 32-kv tile t (4 gl_lds per lane)
    const char* ksrc = kg + (size_t)t * 8192;
    char* kl = smem + buf * 8192;
    int c = w * 64 + lane;            // 0..255
#pragma unroll
    for (int rr = 0; rr < 2; ++rr)
      gl_lds16(ksrc + (size_t)(c + rr * 256) * 16, kl + (c + rr * 256) * 16);
    char* vl = smem + 16384 + buf * 8192;
#pragma unroll
    for (int rr = 0; rr < 2; ++rr) {
      int c2 = c + rr * 256;          // 0..511 within tile
      int h = c2 >> 2, sp = c2 & 3;
      int sl = (sp - (h >> 1)) & 3;
      gl_lds16(vg + (size_t)h * 4096 + (size_t)t * 64 + sl * 16,
               vl + c2 * 16);
    }
  };

  // drain Q loads so in-loop vmcnt sees ONLY stage loads
  asm volatile("s_waitcnt vmcnt(0)" ::: "memory");
  stage(0, 0);

  int cur = 0;
  for (int it = 0; it < ntile; ++it) {
    int t0h = it * 32;
    asm volatile("s_waitcnt vmcnt(0)" ::: "memory");   // stage(it) landed
    __builtin_amdgcn_s_barrier();                      // all waves' stage done

    const char* kb = smem + cur * 8192;
    const char* vbh = smem + 16384 + cur * 8192;
    bool act = (t0h <= qb + 15);

    // K fragments first: ds latency hides under stage-issue
    short8 kf[2][4];
    if (act) read_kf(kb, l15, hi, kf);
    if (it + 1 < ntile) stage(cur ^ 1, it + 1);        // prefetch next tile

    if (act) {
      // QK^T (swapped): lane holds S^T[kv = 4hi+i (+16nt)][q = l15]
      f32x4 sv[2] = {zz, zz};
      __builtin_amdgcn_s_setprio(1);
#pragma unroll
      for (int nt = 0; nt < 2; ++nt)
#pragma unroll
        for (int kk = 0; kk < 4; ++kk)
          sv[nt] = mfma16(kf[nt][kk], qf[kk], sv[nt]);
      __builtin_amdgcn_s_setprio(0);
      // V fragment reads; latency hides under softmax
      short8 vf[8];
      read_vf(vbh, l15, hi, vf);
      bool mask = (t0h + 31 > qb);
      short8 p = mask ? softp_m(sv, t0h, qb, l15, hi, dacc)
                      : softp_u(sv, dacc);
      // PV (V rows pre-permuted to match P k-slot order)
      __builtin_amdgcn_s_setprio(1);
#pragma unroll
      for (int ht = 0; ht < 8; ++ht)
        acc[ht] = mfma16(p, vf[ht], acc[ht]);
      __builtin_amdgcn_s_setprio(0);
    }
    cur ^= 1;
  }

  // denominator: reduce partials across hi (lanes l15 + 16*hi)
  {
    float d = dacc;
    d += __shfl_xor(d, 16);
    d += __shfl_xor(d, 32);
    dacc = d;                        // function of l15 only
  }
  float* dn = out + 8388608;
  if (hi == 0) dn[(size_t)bn * 2048 + qb + l15] = dacc;

  // per-output-row inverse denominators via lane broadcast
  float inv[4];
#pragma unroll
  for (int i = 0; i < 4; ++i)
    inv[i] = __builtin_amdgcn_rcpf(__shfl(dacc, hi * 4 + i));

  // ctx: out[s*4096 + bn*128 + h]; lane holds O[q = qb+4hi+i][h = 16ht+l15]
#pragma unroll
  for (int i = 0; i < 4; ++i) {
    float* orow = out + (size_t)(qb + hi * 4 + i) * 4096 + bn * 128 + l15;
#pragma unroll
    for (int ht = 0; ht < 8; ++ht)
      orow[ht * 16] = acc[ht][i] * inv[i];
  }
}

extern "C" void kernel_launch(void* const* d_in, const int* in_sizes, int n_in,
                              void* d_out, int out_size, void* d_ws, size_t ws_size,
                              hipStream_t stream) {
  const float* Q = (const float*)d_in[0];
  const float* K = (const float*)d_in[1];
  const float* V = (const float*)d_in[2];
  float* out = (float*)d_out;

  unsigned short* kswz = (unsigned short*)d_ws;
  unsigned short* vT   = kswz + (size_t)NHEAD * SEQ * HN;

  prep_kv<<<4608, 256, 0, stream>>>(K, V, kswz, vT);
  attn_main<<<1024, 256, 0, stream>>>(Q, kswz, vT, out);
}

// Round 4
// 85.299 us; speedup vs baseline: 2.1280x; 2.1280x over previous
//
#include <hip/hip_runtime.h>
#include <hip/hip_bf16.h>
#include <stdint.h>

typedef __attribute__((ext_vector_type(8))) short short8;
typedef __attribute__((ext_vector_type(8))) unsigned short ushort8;
typedef __attribute__((ext_vector_type(4))) float f32x4;
typedef __attribute__((ext_vector_type(4))) int int4v;

#define NHEAD 32
#define SEQ   2048
#define HN    128

static constexpr float INV_NORM = 0.08838834764831845f;  // 1/sqrt(128), folded into Q

__device__ __forceinline__ unsigned short f2bf(float f) {
  union { float f; unsigned u; } v; v.f = f;
  unsigned r = v.u + 0x7fffu + ((v.u >> 16) & 1u);   // RNE
  return (unsigned short)(r >> 16);
}

__device__ __forceinline__ f32x4 mfma16(short8 a, short8 b, f32x4 c) {
  return __builtin_amdgcn_mfma_f32_16x16x32_bf16(a, b, c, 0, 0, 0);
}

__device__ __forceinline__ void gl_lds16(const void* g, void* l) {
  __builtin_amdgcn_global_load_lds(
      (const __attribute__((address_space(1))) unsigned int*)g,
      (__attribute__((address_space(3))) unsigned int*)l, 16, 0, 0);
}

// ---- fused prep (unchanged, R3/R5-proven):
__global__ __launch_bounds__(256) void prep_kv(const float* __restrict__ K,
                                               const float* __restrict__ V,
                                               unsigned short* __restrict__ kswz,
                                               unsigned short* __restrict__ vT) {
  __shared__ unsigned short lds[128 * 136];
  int bid = blockIdx.x;
  int tid = threadIdx.x;
  if (bid < 4096) {
    int idx = bid * 256 + tid;     // chunk id: 32*2048*16
    int cl = idx & 15;
    int t  = (idx >> 4) & 2047;
    int bn = idx >> 15;
    const float4* src = (const float4*)(K + ((size_t)t * 32 + bn) * 128 + cl * 8);
    float4 a = src[0], b = src[1];
    ushort8 o;
    o[0]=f2bf(a.x); o[1]=f2bf(a.y); o[2]=f2bf(a.z); o[3]=f2bf(a.w);
    o[4]=f2bf(b.x); o[5]=f2bf(b.y); o[6]=f2bf(b.z); o[7]=f2bf(b.w);
    *(ushort8*)(kswz + ((size_t)bn * 2048 + t) * 128 + ((cl ^ (t & 7)) * 8)) = o;
  } else {
    int vb = bid - 4096;
    int bn = vb >> 4;
    int t0 = (vb & 15) << 7;
    int r = tid >> 1, h0 = (tid & 1) * 64;
    const float* src = V + ((size_t)(t0 + r) * 32 + bn) * 128 + h0;
#pragma unroll
    for (int j = 0; j < 8; ++j) {
      float4 a = *(const float4*)(src + j * 8);
      float4 b = *(const float4*)(src + j * 8 + 4);
      ushort8 o;
      o[0]=f2bf(a.x); o[1]=f2bf(a.y); o[2]=f2bf(a.z); o[3]=f2bf(a.w);
      o[4]=f2bf(b.x); o[5]=f2bf(b.y); o[6]=f2bf(b.z); o[7]=f2bf(b.w);
      *(ushort8*)&lds[r * 136 + h0 + j * 8] = o;
    }
    __syncthreads();
    int h = tid >> 1, ts = (tid & 1) * 64;
    unsigned short tmp[64];
#pragma unroll
    for (int j = 0; j < 64; ++j) {
      int p = j & 31;
      int tloc = ((p >> 3) & 3) * 4 + ((p >> 2) & 1) * 16 + (p & 3);
      tmp[j] = lds[(ts + (j & 32) + tloc) * 136 + h];
    }
    ushort8* dst = (ushort8*)(vT + ((size_t)bn * 128 + h) * 2048 + t0 + ts);
#pragma unroll
    for (int j = 0; j < 8; ++j) dst[j] = *(ushort8*)&tmp[j * 8];
  }
}

// ---- fragment/softmax helpers --------------------------------------------
__device__ __forceinline__ void read_kf(const char* kb, int l15, int hi,
                                        short8 (&kf)[2][4]) {
  int xr = (l15 & 7) << 4;      // (row&7)==(l15&7): nt offset is mult of 16
#pragma unroll
  for (int nt = 0; nt < 2; ++nt) {
    const char* krow = kb + (nt * 16 + l15) * 256;
#pragma unroll
    for (int kk = 0; kk < 4; ++kk)
      kf[nt][kk] = *(const short8*)(krow + (((kk * 4 + hi) * 16) ^ xr));
  }
}

__device__ __forceinline__ void read_vf(const char* vbh, int l15, int hi,
                                        short8 (&vf)[8]) {
#pragma unroll
  for (int ht = 0; ht < 8; ++ht)
    vf[ht] = *(const short8*)(vbh + (ht * 16 + l15) * 64 +
                              ((((l15 >> 1) + hi) & 3) * 16));
}

__device__ __forceinline__ short8 packp(const float (&e)[8], float& da) {
  da += ((e[0] + e[1]) + (e[2] + e[3])) + ((e[4] + e[5]) + (e[6] + e[7]));
  unsigned w0, w1, w2, w3;
  asm("v_cvt_pk_bf16_f32 %0, %1, %2" : "=v"(w0) : "v"(e[0]), "v"(e[1]));
  asm("v_cvt_pk_bf16_f32 %0, %1, %2" : "=v"(w1) : "v"(e[2]), "v"(e[3]));
  asm("v_cvt_pk_bf16_f32 %0, %1, %2" : "=v"(w2) : "v"(e[4]), "v"(e[5]));
  asm("v_cvt_pk_bf16_f32 %0, %1, %2" : "=v"(w3) : "v"(e[6]), "v"(e[7]));
  union { int4v u; short8 s; } pk;
  pk.u = (int4v){(int)w0, (int)w1, (int)w2, (int)w3};
  return pk.s;
}

// Q pre-scaled by 1/sqrt(128): probability = exp(S) directly.
__device__ __forceinline__ short8 softp_m(const f32x4 (&sv)[2], int t0h, int qbase,
                                          int l15, int hi, float& da) {
  float e[8];
#pragma unroll
  for (int nt = 0; nt < 2; ++nt)
#pragma unroll
    for (int i = 0; i < 4; ++i) {
      float x = __expf(sv[nt][i]);
      int kv = t0h + nt * 16 + hi * 4 + i;
      e[nt * 4 + i] = (kv <= qbase + l15) ? x : 0.0f;
    }
  return packp(e, da);
}

__device__ __forceinline__ short8 softp_u(const f32x4 (&sv)[2], float& da) {
  float e[8];
#pragma unroll
  for (int nt = 0; nt < 2; ++nt)
#pragma unroll
    for (int i = 0; i < 4; ++i)
      e[nt * 4 + i] = __expf(sv[nt][i]);
  return packp(e, da);
}

// ---- main: 1024 blocks x 256 threads, each block = ONE 64-row q-tile,
// 4 waves x 16 q-rows, KVB=32 double-buffered (32KB LDS) -> 4 blocks/CU
// resident (grid = exactly 4/CU), 16 waves/CU = 4 waves/SIMD.
// __launch_bounds__ min-waves arg caps VGPRs at 256/w (R1/R3 evidence:
// w=4 -> 64 regs -> spill catastrophe).  Use w=2 (cap 128): HW still runs
// 4 waves/SIMD for any usage <=128 (m69 brackets), no spill.
// Work balance: co-resident set {z, z+8, z+16, z+24} sums to 62 units;
// heaviest blocks get lowest bids (dispatched first).
__global__ __launch_bounds__(256, 2) void attn_main(const float* __restrict__ Q,
                                                    const unsigned short* __restrict__ kswz,
                                                    const unsigned short* __restrict__ vT,
                                                    float* __restrict__ out) {
  // LDS: K 2x8KB | V 2x8KB = 32768
  __shared__ char smem[32768];
  int tid = threadIdx.x;
  int lane = tid & 63;
  int w = tid >> 6;
  int l15 = lane & 15;
  int hi = lane >> 4;

  int bid = blockIdx.x;
  int bn = bid & 31;                    // head -> XCD bid%8 = bn%8 (stable)
  int z = bid >> 5;                     // [0,32)
  int g = z & 7, s = z >> 3;
  int qt = (s == 0) ? (31 - g) : (s == 1) ? (16 + g) : (s == 2) ? (15 - g) : g;
  int qb = qt * 64 + w * 16;            // this wave's 16 q-rows
  int ntile = 2 * qt + 2;               // 32-kv tiles

  // Q B-fragments, PRE-SCALED by 1/sqrt(128): softmax is exp(S) direct.
  short8 qf[4];
  {
    const float* qrow = Q + ((size_t)(qb + l15) * 32 + bn) * 128;
#pragma unroll
    for (int kk = 0; kk < 4; ++kk) {
      float4 a = *(const float4*)(qrow + kk * 32 + hi * 8);
      float4 b = *(const float4*)(qrow + kk * 32 + hi * 8 + 4);
      short8 o;
      o[0]=(short)f2bf(a.x*INV_NORM); o[1]=(short)f2bf(a.y*INV_NORM);
      o[2]=(short)f2bf(a.z*INV_NORM); o[3]=(short)f2bf(a.w*INV_NORM);
      o[4]=(short)f2bf(b.x*INV_NORM); o[5]=(short)f2bf(b.y*INV_NORM);
      o[6]=(short)f2bf(b.z*INV_NORM); o[7]=(short)f2bf(b.w*INV_NORM);
      qf[kk] = o;
    }
  }

  f32x4 zz = {0.f, 0.f, 0.f, 0.f};
  f32x4 acc[8];
#pragma unroll
  for (int ht = 0; ht < 8; ++ht) acc[ht] = zz;
  float dacc = 0.f;

  const char* kg = (const char*)(kswz + (size_t)bn * 2048 * 128);
  const char* vg = (const char*)(vT + (size_t)bn * 128 * 2048);

  auto stage = [&](int buf, int t) {  // stage 32-kv tile t (4 gl_lds per lane)
    const char* ksrc = kg + (size_t)t * 8192;
    char* kl = smem + buf * 8192;
    int c = w * 64 + lane;            // 0..255
#pragma unroll
    for (int rr = 0; rr < 2; ++rr)
      gl_lds16(ksrc + (size_t)(c + rr * 256) * 16, kl + (c + rr * 256) * 16);
    char* vl = smem + 16384 + buf * 8192;
#pragma unroll
    for (int rr = 0; rr < 2; ++rr) {
      int c2 = c + rr * 256;          // 0..511 within tile
      int h = c2 >> 2, sp = c2 & 3;
      int sl = (sp - (h >> 1)) & 3;
      gl_lds16(vg + (size_t)h * 4096 + (size_t)t * 64 + sl * 16,
               vl + c2 * 16);
    }
  };

  // drain Q loads so in-loop vmcnt sees ONLY stage loads
  asm volatile("s_waitcnt vmcnt(0)" ::: "memory");
  stage(0, 0);

  int cur = 0;
  for (int it = 0; it < ntile; ++it) {
    int t0h = it * 32;
    asm volatile("s_waitcnt vmcnt(0)" ::: "memory");   // stage(it) landed
    __builtin_amdgcn_s_barrier();                      // all waves' stage done

    const char* kb = smem + cur * 8192;
    const char* vbh = smem + 16384 + cur * 8192;
    bool act = (t0h <= qb + 15);

    // K fragments first: ds latency hides under stage-issue
    short8 kf[2][4];
    if (act) read_kf(kb, l15, hi, kf);
    if (it + 1 < ntile) stage(cur ^ 1, it + 1);        // prefetch next tile

    if (act) {
      // QK^T (swapped): lane holds S^T[kv = 4hi+i (+16nt)][q = l15]
      f32x4 sv[2] = {zz, zz};
      __builtin_amdgcn_s_setprio(1);
#pragma unroll
      for (int nt = 0; nt < 2; ++nt)
#pragma unroll
        for (int kk = 0; kk < 4; ++kk)
          sv[nt] = mfma16(kf[nt][kk], qf[kk], sv[nt]);
      __builtin_amdgcn_s_setprio(0);
      // V fragment reads; latency hides under softmax
      short8 vf[8];
      read_vf(vbh, l15, hi, vf);
      bool mask = (t0h + 31 > qb);
      short8 p = mask ? softp_m(sv, t0h, qb, l15, hi, dacc)
                      : softp_u(sv, dacc);
      // PV (V rows pre-permuted to match P k-slot order)
      __builtin_amdgcn_s_setprio(1);
#pragma unroll
      for (int ht = 0; ht < 8; ++ht)
        acc[ht] = mfma16(p, vf[ht], acc[ht]);
      __builtin_amdgcn_s_setprio(0);
    }
    cur ^= 1;
  }

  // denominator: reduce partials across hi (lanes l15 + 16*hi)
  {
    float d = dacc;
    d += __shfl_xor(d, 16);
    d += __shfl_xor(d, 32);
    dacc = d;                        // function of l15 only
  }
  float* dn = out + 8388608;
  if (hi == 0) dn[(size_t)bn * 2048 + qb + l15] = dacc;

  // per-output-row inverse denominators via lane broadcast
  float inv[4];
#pragma unroll
  for (int i = 0; i < 4; ++i)
    inv[i] = __builtin_amdgcn_rcpf(__shfl(dacc, hi * 4 + i));

  // ctx: out[s*4096 + bn*128 + h]; lane holds O[q = qb+4hi+i][h = 16ht+l15]
#pragma unroll
  for (int i = 0; i < 4; ++i) {
    float* orow = out + (size_t)(qb + hi * 4 + i) * 4096 + bn * 128 + l15;
#pragma unroll
    for (int ht = 0; ht < 8; ++ht)
      orow[ht * 16] = acc[ht][i] * inv[i];
  }
}

extern "C" void kernel_launch(void* const* d_in, const int* in_sizes, int n_in,
                              void* d_out, int out_size, void* d_ws, size_t ws_size,
                              hipStream_t stream) {
  const float* Q = (const float*)d_in[0];
  const float* K = (const float*)d_in[1];
  const float* V = (const float*)d_in[2];
  float* out = (float*)d_out;

  unsigned short* kswz = (unsigned short*)d_ws;
  unsigned short* vT   = kswz + (size_t)NHEAD * SEQ * HN;

  prep_kv<<<4608, 256, 0, stream>>>(K, V, kswz, vT);
  attn_main<<<1024, 256, 0, stream>>>(Q, kswz, vT, out);
}